// Round 13
// baseline (127.806 us; speedup 1.0000x reference)
//
#include <hip/hip_runtime.h>

#define DEVI __device__ __forceinline__

constexpr int N_ = 2, C_ = 80, H_ = 32, W_ = 40, HW_ = H_ * W_, HWC_ = HW_ * C_;
constexpr int KTOP = 1000, M2_ = 196;
constexpr int IMH = 256, IMW = 320;
constexpr int NB = 2048;          // f32-derived bins
constexpr int KB = 16;            // hist slices per image
constexpr int SLICE = HWC_ / KB;  // 6400 = 5*HW_
constexpr int BCAP = 2048;        // rank working-set cap (expected G ~ 1100)
constexpr int GCAP = 4096;        // global buf cap
constexpr unsigned MAGIC = 0x5EEDFACEu;

// output layout (floats): bx[2][100][4] | sc[2][100] | lb[2][100] | prob[2][100][196] | vf[2][100]
constexpr int O_SC = 800, O_LB = 1000, O_PB = 1200, O_VF = 40400;

DEVI unsigned long long mapd(double v) {
  unsigned long long u = (unsigned long long)__double_as_longlong(v);
  return (u & 0x8000000000000000ull) ? ~u : (u | 0x8000000000000000ull);
}
DEVI double unmapd(unsigned long long k) {
  unsigned long long u = (k & 0x8000000000000000ull) ? (k ^ 0x8000000000000000ull) : ~k;
  return __longlong_as_double((long long)u);
}
DEVI int i0of(int x, int cap) {  // exact first contributing mask row/col (matches table arithmetic)
  float src = ((float)x + 0.5f) * 0.125f - 0.5f;
  src = fminf(fmaxf(src, 0.f), (float)cap);
  return (int)floorf(src);
}

// flags: [0..31]=hist-ready magic  [32..63]=compact-ready magic  [64..65]=nmsCnt
DEVI unsigned aload(unsigned* p) { return atomicAdd(p, 0u); }

struct SliceSh {
  unsigned hist[NB];
  float ce[HW_];
  unsigned wtot[16], wabove[16], sliceCnt[16], sliceOff[17];
  unsigned sD, lcnt;
};
struct RankSh {
  unsigned long long K[BCAP];
  unsigned I[BCAP];
  unsigned short eb[BCAP];
  unsigned short ord[BCAP];
  unsigned bh[NB], bs[NB], cur[NB];
  unsigned long long Ks[1024];
  unsigned Is[1024];
  unsigned wtot[16], wabove[16];
};
struct MaskSh { float tile[4][32][33]; };
union ShA { SliceSh s; RankSh r; MaskSh m; };

// ===== K_A: hist -> (handshake) -> compact -> (handshake) -> rank+decode | mask | tables =====
__global__ __launch_bounds__(1024) void k_a(const float* cls, const float* cent, const float* bm,
                                            const float* loc, const float* breg,
                                            unsigned* ghist, unsigned long long* bufK, unsigned* bufI,
                                            double* bxd, double* scd, int* lab, int* vld, int* rg,
                                            unsigned* keepg, float* msig, float* wr, float* wc,
                                            unsigned* flags) {
  __shared__ ShA sh;
  int b = blockIdx.x, tid = threadIdx.x, lane = tid & 63, wid = tid >> 6;

  if (b < N_ * KB) {
    int n = b >> 4, sb = b & 15;
    size_t gbase = (size_t)n * HWC_ + (size_t)sb * SLICE;
    // ---- phase 1: per-slice hist (r12 k_pre verbatim) ----
    for (int j = tid; j < NB; j += 1024) sh.s.hist[j] = 0;
    for (int j = tid; j < HW_; j += 1024) sh.s.ce[j] = 1.f / (1.f + expf(-cent[n * HW_ + j]));
    __syncthreads();
    #pragma unroll
    for (int it = 0; it < 7; ++it) {
      int j = it * 1024 + tid;
      if (j < SLICE) {
        float aa = cls[gbase + j];
        float s = 1.f / (1.f + expf(-aa));
        // conservative band: f32 s <= 0.0499999 implies exact sigmoid < 0.05 (r6-r12-proven)
        if (s > 0.0499999f) {
          unsigned key = __float_as_uint(s * sh.s.ce[j % HW_]);
          int bin = (int)(key >> 16) - 0x3800;
          bin = bin < 0 ? 0 : (bin > NB - 1 ? NB - 1 : bin);
          atomicAdd(&sh.s.hist[bin], 1u);
        }
      }
    }
    __syncthreads();
    unsigned* gh = ghist + ((size_t)n * KB + sb) * NB;
    for (int j = tid; j < NB; j += 1024) gh[j] = sh.s.hist[j];
    __threadfence();
    if (tid == 0) atomicExch(&flags[n * 16 + sb], MAGIC);
    // ---- handshake 1: wait all 16 slice hists of this image ----
    if (tid == 0) { for (int q = 0; q < 16; ++q) while (aload(&flags[n * 16 + q]) != MAGIC) {} }
    __syncthreads();
    __threadfence();
    // ---- phase 2: compact (r12 k_compact body) ----
    {
      const unsigned* ghn = ghist + (size_t)n * KB * NB;
      unsigned a = 0, bv = 0;
      #pragma unroll
      for (int q = 0; q < KB; ++q) { a += ghn[q * NB + 2 * tid]; bv += ghn[q * NB + 2 * tid + 1]; }
      if (tid == 0) { sh.s.sD = 0; sh.s.lcnt = 0; }
      unsigned s2 = a + bv, suf = s2;
      for (int off = 1; off < 64; off <<= 1) {
        unsigned v = __shfl_down(suf, off);
        if (lane + off < 64) suf += v;
      }
      if (lane == 0) sh.s.wtot[wid] = suf;
      __syncthreads();
      if (tid == 0) { unsigned acc = 0; for (int w = 15; w >= 0; --w) { sh.s.wabove[w] = acc; acc += sh.s.wtot[w]; } }
      __syncthreads();
      unsigned above = (suf - s2) + sh.s.wabove[wid];
      if (above < 1000u && above + bv >= 1000u) sh.s.sD = (unsigned)(2 * tid + 1);
      if (above + bv < 1000u && above + bv + a >= 1000u) sh.s.sD = (unsigned)(2 * tid);
      __syncthreads();
      unsigned D = sh.s.sD;
      unsigned Dg = (D > 0) ? D - 1 : 0;      // guard bin covers f32-vs-f64 straddle (r6-proven)
      {
        unsigned acc = 0;
        for (int bin = (int)Dg + lane; bin < NB; bin += 64) acc += ghn[wid * NB + bin];
        for (int off = 32; off; off >>= 1) acc += __shfl_down(acc, off);
        if (lane == 0) sh.s.sliceCnt[wid] = acc;
      }
      __syncthreads();
      if (tid == 0) {
        unsigned acc = 0;
        for (int q = 0; q < KB; ++q) { sh.s.sliceOff[q] = acc; acc += sh.s.sliceCnt[q]; }
        sh.s.sliceOff[KB] = acc;
      }
      __syncthreads();
      unsigned myStart = sh.s.sliceOff[sb];
      for (int it = 0; it < 7; ++it) {
        int j = it * 1024 + tid;
        bool win = false; float aa = 0.f;
        if (j < SLICE) {
          aa = cls[gbase + j];
          float s = 1.f / (1.f + expf(-aa));
          if (s > 0.0499999f) {
            unsigned key = __float_as_uint(s * sh.s.ce[j % HW_]);
            int bin = (int)(key >> 16) - 0x3800;
            bin = bin < 0 ? 0 : (bin > NB - 1 ? NB - 1 : bin);
            win = ((unsigned)bin >= Dg);
          }
        }
        unsigned long long mb = __ballot(win);
        if (mb) {
          int lead = __builtin_ctzll(mb);
          unsigned offw = 0;
          if (lane == lead) offw = atomicAdd(&sh.s.lcnt, (unsigned)__popcll(mb));
          offw = (unsigned)__shfl((int)offw, lead);
          if (win) {
            unsigned pos = myStart + offw + (unsigned)__popcll(mb & ((1ull << lane) - 1ull));
            if (pos < (unsigned)GCAP) {
              int hw = j % HW_, c = sb * 5 + j / HW_;   // SLICE = 5*HW_
              double ss = 1.0 / (1.0 + exp(-(double)aa));
              double ced = 1.0 / (1.0 + exp(-(double)cent[n * HW_ + hw]));
              double v = (ss > 0.05) ? ss * ced : -1e9; // exact reference gate + key
              bufK[(size_t)n * GCAP + pos] = mapd(v);
              bufI[(size_t)n * GCAP + pos] = (unsigned)(hw * C_ + c);  // logical [HW,C] index
            }
          }
        }
      }
    }
    int G = (int)sh.s.sliceOff[KB];
    __threadfence();
    if (tid == 0) atomicExch(&flags[32 + n * 16 + sb], MAGIC);
    if (sb != 0) return;
    // ---- handshake 2: block sb==0 waits for all 16 compact flags ----
    if (tid == 0) { for (int q = 0; q < 16; ++q) while (aload(&flags[32 + n * 16 + q]) != MAGIC) {} }
    __syncthreads();
    __threadfence();
    // ---- phase 3: rank + decode (r12 k_rankdec body; G from register) ----
    if (G > BCAP) G = BCAP;
    for (int j = tid; j < NB; j += 1024) sh.r.bh[j] = 0;
    for (int p = tid; p < G; p += 1024) {
      sh.r.K[p] = bufK[(size_t)n * GCAP + p];
      sh.r.I[p] = bufI[(size_t)n * GCAP + p];
    }
    __syncthreads();
    for (int p = tid; p < G; p += 1024) {
      double v = unmapd(sh.r.K[p]);
      int bb = 0;
      if (v > 0.0) {                          // monotone f64->f32 cast => exact bucket order
        unsigned kb = __float_as_uint((float)v);
        bb = (int)(kb >> 16) - 0x3800;
        bb = bb < 0 ? 0 : (bb > NB - 1 ? NB - 1 : bb);
      }
      sh.r.eb[p] = (unsigned short)bb;
      atomicAdd(&sh.r.bh[bb], 1u);
    }
    __syncthreads();
    {
      unsigned a2 = sh.r.bh[2 * tid], b2 = sh.r.bh[2 * tid + 1];
      unsigned s3 = a2 + b2, suf2 = s3;
      for (int off = 1; off < 64; off <<= 1) {
        unsigned v = __shfl_down(suf2, off);
        if (lane + off < 64) suf2 += v;
      }
      if (lane == 0) sh.r.wtot[wid] = suf2;
      __syncthreads();
      if (tid == 0) { unsigned acc = 0; for (int w = 15; w >= 0; --w) { sh.r.wabove[w] = acc; acc += sh.r.wtot[w]; } }
      __syncthreads();
      unsigned above2 = (suf2 - s3) + sh.r.wabove[wid];
      sh.r.bs[2 * tid + 1] = above2;  sh.r.cur[2 * tid + 1] = above2;
      sh.r.bs[2 * tid] = above2 + b2; sh.r.cur[2 * tid] = above2 + b2;
    }
    __syncthreads();
    for (int p = tid; p < G; p += 1024) {
      unsigned p2 = atomicAdd(&sh.r.cur[sh.r.eb[p]], 1u);
      sh.r.ord[p2] = (unsigned short)p;
    }
    __syncthreads();
    for (int p = tid; p < G; p += 1024) {
      int bb = sh.r.eb[p];
      unsigned lo = sh.r.bs[bb], len = sh.r.bh[bb];
      unsigned long long k1 = sh.r.K[p]; unsigned i1 = sh.r.I[p];
      unsigned r = lo;
      for (unsigned q = lo; q < lo + len; ++q) {
        int j = sh.r.ord[q];
        unsigned long long kj = sh.r.K[j]; unsigned ij = sh.r.I[j];
        if ((kj > k1) || (kj == k1 && ij < i1)) ++r;
      }
      if (r < 1024u) { sh.r.Ks[r] = k1; sh.r.Is[r] = i1; }
    }
    for (int j = G + tid; j < 1024; j += 1024) { sh.r.Ks[j] = 0ull; sh.r.Is[j] = 0xFFFFFFFFu; }
    __syncthreads();
    // decode top-1000 (f64, exact vs np ref; verbatim r12)
    if (tid < KTOP) {
      unsigned long long key = sh.r.Ks[tid];
      unsigned idx = sh.r.Is[tid];
      double v = unmapd(key);
      int valid = (v > -5e8) && (idx < (unsigned)HWC_);
      if (idx >= (unsigned)HWC_) idx = 0;
      int hw = (int)(idx / C_), c = (int)(idx % C_);
      double lx = (double)loc[hw * 2 + 0], ly = (double)loc[hw * 2 + 1];
      const float* rg4 = breg + (size_t)n * 4 * HW_;
      double r0 = (double)rg4[0 * HW_ + hw], r1 = (double)rg4[1 * HW_ + hw];
      double r2 = (double)rg4[2 * HW_ + hw], r3 = (double)rg4[3 * HW_ + hw];
      double b0 = lx - r0, b1 = ly - r1, b2 = lx + r2, b3 = ly + r3;
      double sc = valid ? sqrt(v) : 0.0;
      int bi0 = (int)b0, bi1 = (int)b1, bi2 = (int)b2, bi3 = (int)b3;
      int x1 = max(bi0, 0), x2 = min(bi2, IMH - 1), y1 = max(bi1, 0), y2 = min(bi3, IMW - 1);
      int rok = (x1 < x2) && (y1 < x2) && (y1 < y2);   // ref bug replicated
      int x1c = min(max(x1, 0), IMH), x2c = min(max(x2, 0), IMH);
      int y1c = min(max(y1, 0), IMW), y2c = min(max(y2, 0), IMW);
      int area = max((x2c - x1c) * (y2c - y1c), 1);
      double c0 = fmin(fmax(b0, 0.0), (double)(IMW - 1));
      double c1 = fmin(fmax(b1, 0.0), (double)(IMH - 1));
      double c2 = fmin(fmax(b2, 0.0), (double)(IMW - 1));
      double c3 = fmin(fmax(b3, 0.0), (double)(IMH - 1));
      size_t base = (size_t)n * 1024 + tid;
      bxd[base * 4 + 0] = c0; bxd[base * 4 + 1] = c1; bxd[base * 4 + 2] = c2; bxd[base * 4 + 3] = c3;
      scd[base] = sc; lab[base] = c + 1; vld[base] = valid;
      int* r8 = rg + base * 8;
      r8[0] = x1c; r8[1] = x2c; r8[2] = y1c; r8[3] = y2c; r8[4] = area; r8[5] = rok;
    }
    for (int j = tid; j < 1024; j += 1024) keepg[n * 1024 + j] = 0;
    __syncthreads();
    if (tid == 0) {
      flags[64 + n] = 0;                     // nmsCnt for K_B (kernel-boundary visibility)
      for (int q = 0; q < 16; ++q) { flags[n * 16 + q] = 0; flags[32 + n * 16 + q] = 0; }
    }
  } else if (b < N_ * KB + 140) {
    // ---- mask transpose + sigmoid (r12 verbatim) ----
    int g = tid >> 8, sub = tid & 255;
    int tt = (b - N_ * KB) * 4 + g;           // 0..559
    int n = tt / 280, r = tt % 280, rqt = r / 7, ct = r % 7;
    int tx = sub & 31, ty = sub >> 5;         // 32x8
    int rq0 = rqt * 32, c0 = ct * 32;
    for (int i = 0; i < 4; ++i) {
      int cc = c0 + ty + i * 8, rq = rq0 + tx;
      if (cc < M2_) {
        float v = bm[((size_t)n * M2_ + cc) * HW_ + rq];
        sh.m.tile[g][ty + i * 8][tx] = 1.f / (1.f + expf(-v));
      }
    }
    __syncthreads();
    for (int i = 0; i < 4; ++i) {
      int rq = rq0 + ty + i * 8, cc = c0 + tx;
      if (cc < M2_) msig[((size_t)n * HW_ + rq) * M2_ + cc] = sh.m.tile[g][tx][ty + i * 8];
    }
  } else {
    // ---- bilinear cumulative weight tables (r12 verbatim) ----
    int t = tid;
    if (t < H_) {
      int r = t; float acc = 0.f; wr[0 * H_ + r] = 0.f;
      for (int x = 0; x < IMH; ++x) {
        float src = ((float)x + 0.5f) * ((float)H_ / (float)IMH) - 0.5f;
        src = fminf(fmaxf(src, 0.f), (float)(H_ - 1));
        int i0 = (int)floorf(src); int i1 = min(i0 + 1, H_ - 1);
        float lam = src - (float)i0;
        float w = ((r == i0) ? (1.f - lam) : 0.f) + ((r == i1) ? lam : 0.f);
        acc += w; wr[(x + 1) * H_ + r] = acc;
      }
    } else if (t < H_ + W_) {
      int q = t - H_; float acc = 0.f; wc[0 * W_ + q] = 0.f;
      for (int y = 0; y < IMW; ++y) {
        float src = ((float)y + 0.5f) * ((float)W_ / (float)IMW) - 0.5f;
        src = fminf(fmaxf(src, 0.f), (float)(W_ - 1));
        int i0 = (int)floorf(src); int i1 = min(i0 + 1, W_ - 1);
        float lam = src - (float)i0;
        float w = ((q == i0) ? (1.f - lam) : 0.f) + ((q == i1) ? lam : 0.f);
        acc += w; wc[(y + 1) * W_ + q] = acc;
      }
    }
  }
}

// ===== K_B: blocks [0,160) = single-wave NMS (r7-proven); [160,360) = finish (r5-proven) =====
struct NmsSh { double bx[128][5]; unsigned short ml[128]; };
struct FinSh { int lsel[100], lvf[100]; unsigned woff[4]; unsigned sS; float A[H_], Bw[W_]; };
union ShB { NmsSh nm; FinSh fn; };

__global__ __launch_bounds__(256) void k_b(const double* bxd, const double* scd, const int* lab,
                                           const int* vld, const int* rg, unsigned* keepg,
                                           const float* msig, const float* wr, const float* wc,
                                           unsigned* flags, float* out) {
  __shared__ ShB sh;
  int b = blockIdx.x, tid = threadIdx.x, lane = tid & 63, wid = tid >> 6;

  if (b < N_ * C_) {
    // ---- NMS role: one class, one wave, register kept-masks (r7/r11-proven) ----
    int n = b / C_, cls_ = b % C_ + 1;
    if (tid < 64) {
      int m = 0;
      for (int ch = 0; ch < 16; ++ch) {
        int e = ch * 64 + lane;
        bool pred = (e < KTOP) && vld[n * 1024 + e] && (lab[n * 1024 + e] == cls_);
        unsigned long long bb = __ballot(pred);
        if (pred) {
          int pos = m + (int)__popcll(bb & ((1ull << lane) - 1ull));
          if (pos < 128) {
            const double* p = bxd + ((size_t)n * 1024 + e) * 4;
            double b0 = p[0], b1 = p[1], b2 = p[2], b3 = p[3];
            sh.nm.bx[pos][0] = b0; sh.nm.bx[pos][1] = b1; sh.nm.bx[pos][2] = b2; sh.nm.bx[pos][3] = b3;
            sh.nm.bx[pos][4] = (b2 - b0 + 1.0) * (b3 - b1 + 1.0);
            sh.nm.ml[pos] = (unsigned short)e;
          }
        }
        m += (int)__popcll(bb);
      }
      if (m > 128) m = 128;
      __builtin_amdgcn_wave_barrier();
      unsigned long long k0 = (m >= 64) ? ~0ull : ((1ull << m) - 1ull);
      unsigned long long k1m = (m > 64) ? ((m >= 128) ? ~0ull : ((1ull << (m - 64)) - 1ull)) : 0ull;
      for (int i = 0; i < m; ++i) {
        bool alive = (i < 64) ? ((k0 >> i) & 1ull) : ((k1m >> (i - 64)) & 1ull);
        if (!alive) continue;                 // uniform across lanes
        double x1 = sh.nm.bx[i][0], y1 = sh.nm.bx[i][1], x2 = sh.nm.bx[i][2], y2 = sh.nm.bx[i][3], ai = sh.nm.bx[i][4];
        {
          int j = lane;
          bool ok = (j < m) && (j > i);
          int jj = ok ? j : 0;
          double u1 = sh.nm.bx[jj][0], v1 = sh.nm.bx[jj][1], u2 = sh.nm.bx[jj][2], v2 = sh.nm.bx[jj][3], aj = sh.nm.bx[jj][4];
          double ltx = fmax(x1, u1), lty = fmax(y1, v1), rbx = fmin(x2, u2), rby = fmin(y2, v2);
          double iw = fmax(rbx - ltx + 1.0, 0.0), ih = fmax(rby - lty + 1.0, 0.0);
          double inter = iw * ih, uni = ai + aj - inter;
          bool sup = ok && (inter / fmax(uni, 1e-6) > 0.6);
          k0 &= ~__ballot(sup);
        }
        if (m > 64) {
          int j = 64 + lane;
          bool ok = (j < m) && (j > i);
          int jj = ok ? j : 0;
          double u1 = sh.nm.bx[jj][0], v1 = sh.nm.bx[jj][1], u2 = sh.nm.bx[jj][2], v2 = sh.nm.bx[jj][3], aj = sh.nm.bx[jj][4];
          double ltx = fmax(x1, u1), lty = fmax(y1, v1), rbx = fmin(x2, u2), rby = fmin(y2, v2);
          double iw = fmax(rbx - ltx + 1.0, 0.0), ih = fmax(rby - lty + 1.0, 0.0);
          double inter = iw * ih, uni = ai + aj - inter;
          bool sup = ok && (inter / fmax(uni, 1e-6) > 0.6);
          k1m &= ~__ballot(sup);
        }
      }
      for (int j = lane; j < m; j += 64) {
        bool kb2 = (j < 64) ? ((k0 >> j) & 1ull) : ((k1m >> (j - 64)) & 1ull);
        keepg[n * 1024 + sh.nm.ml[j]] = kb2 ? 1u : 0u;
      }
    }
    __threadfence();
    if (tid == 0) atomicAdd(&flags[64 + n], 1u);
  } else {
    // ---- finish role: wait for all 80 classes of this image, then r5-verbatim finish ----
    int idx = b - N_ * C_;
    int n = idx / 100, t = idx % 100;
    if (tid == 0) { while (aload(&flags[64 + n]) < (unsigned)C_) {} }
    __syncthreads();
    __threadfence();

    int i0 = tid * 4;
    unsigned ff[4]; int lc = 0;
    for (int j = 0; j < 4; ++j) {
      int i = i0 + j;
      ff[j] = (i < KTOP) ? keepg[n * 1024 + i] : 0u;
      lc += (int)ff[j];
    }
    unsigned pre = (unsigned)lc;
    for (int off = 1; off < 64; off <<= 1) {
      unsigned v = __shfl_up(pre, off);
      if (lane >= off) pre += v;
    }
    if (lane == 63) sh.fn.woff[wid] = pre;
    __syncthreads();
    if (tid == 0) { unsigned acc = 0; for (int w = 0; w < 4; ++w) { unsigned tmp = sh.fn.woff[w]; sh.fn.woff[w] = acc; acc += tmp; } sh.fn.sS = acc; }
    __syncthreads();
    int kpre = (int)(sh.fn.woff[wid] + pre - (unsigned)lc);
    int S = (int)sh.fn.sS;
    for (int j = 0; j < 4; ++j) {
      int i = i0 + j;
      if (i < KTOP) {
        if (ff[j]) { if (kpre < 100) { sh.fn.lsel[kpre] = i; sh.fn.lvf[kpre] = 1; } kpre++; }
        else { int slot = S + (i - kpre); if (slot < 100) { sh.fn.lsel[slot] = i; sh.fn.lvf[slot] = 0; } }
      }
    }
    __syncthreads();

    int k = sh.fn.lsel[t], vf = sh.fn.lvf[t];
    if (tid == 0) {
      const double* bb = bxd + ((size_t)n * 1024 + k) * 4;
      out[(n * 100 + t) * 4 + 0] = (float)bb[0];
      out[(n * 100 + t) * 4 + 1] = (float)bb[1];
      out[(n * 100 + t) * 4 + 2] = (float)bb[2];
      out[(n * 100 + t) * 4 + 3] = (float)bb[3];
      out[O_SC + n * 100 + t] = vf ? (float)scd[n * 1024 + k] : 0.f;
      out[O_LB + n * 100 + t] = (float)lab[n * 1024 + k];
      out[O_VF + n * 100 + t] = (float)vf;
    }
    const int* r8 = rg + ((size_t)n * 1024 + k) * 8;
    int x1c = r8[0], x2c = r8[1], y1c = r8[2], y2c = r8[3], area = r8[4], rok = r8[5];
    if (tid < H_) sh.fn.A[tid] = wr[x2c * H_ + tid] - wr[x1c * H_ + tid];
    else if (tid < H_ + W_) { int q = tid - H_; sh.fn.Bw[q] = wc[y2c * W_ + q] - wc[y1c * W_ + q]; }
    __syncthreads();
    if (tid < M2_) {
      float acc = 0.f;
      if (rok && vf) {
        int rlo = i0of(x1c, H_ - 1);
        int rhi = min(i0of(x2c - 1, H_ - 1) + 1, H_ - 1);
        int qlo = i0of(y1c, W_ - 1);
        int qhi = min(i0of(y2c - 1, W_ - 1) + 1, W_ - 1);
        for (int r = rlo; r <= rhi; ++r) {
          float ar = sh.fn.A[r];
          const float* mrow = msig + ((size_t)((n * H_ + r) * W_ + qlo)) * M2_ + tid;
          float rs = 0.f;
          #pragma unroll 4
          for (int q = qlo; q <= qhi; ++q) { rs += sh.fn.Bw[q] * mrow[0]; mrow += M2_; }
          acc += ar * rs;
        }
        acc /= (float)area;
      }
      out[O_PB + (size_t)(n * 100 + t) * M2_ + tid] = acc;
    }
  }
}

extern "C" void kernel_launch(void* const* d_in, const int* in_sizes, int n_in,
                              void* d_out, int out_size, void* d_ws, size_t ws_size,
                              hipStream_t stream) {
  (void)in_sizes; (void)n_in; (void)out_size; (void)ws_size;
  const float* locations = (const float*)d_in[0];
  const float* box_cls   = (const float*)d_in[1];
  const float* box_reg   = (const float*)d_in[2];
  const float* cent      = (const float*)d_in[3];
  const float* box_mask  = (const float*)d_in[4];
  float* out = (float*)d_out;

  char* ws = (char*)d_ws;
  size_t off = 0;
  auto alloc = [&](size_t bytes) -> void* {
    void* p = ws + off;
    off = (off + bytes + 255) & ~(size_t)255;
    return p;
  };
  unsigned* ghist          = (unsigned*)alloc((size_t)N_ * KB * NB * 4);
  unsigned long long* bufK = (unsigned long long*)alloc((size_t)N_ * GCAP * 8);
  unsigned* bufI           = (unsigned*)alloc((size_t)N_ * GCAP * 4);
  double* bxd              = (double*)alloc((size_t)N_ * 1024 * 4 * 8);
  double* scd              = (double*)alloc((size_t)N_ * 1024 * 8);
  int* lab                 = (int*)alloc((size_t)N_ * 1024 * 4);
  int* vld                 = (int*)alloc((size_t)N_ * 1024 * 4);
  int* rg                  = (int*)alloc((size_t)N_ * 1024 * 8 * 4);
  unsigned* keepg          = (unsigned*)alloc((size_t)N_ * 1024 * 4);
  float* msig              = (float*)alloc((size_t)N_ * HW_ * M2_ * 4);
  float* wr                = (float*)alloc((size_t)(IMH + 1) * H_ * 4);
  float* wc                = (float*)alloc((size_t)(IMW + 1) * W_ * 4);
  unsigned* flags          = (unsigned*)alloc(128 * 4);

  k_a<<<N_ * KB + 140 + 1, 1024, 0, stream>>>(box_cls, cent, box_mask, locations, box_reg,
                                              ghist, bufK, bufI, bxd, scd, lab, vld, rg,
                                              keepg, msig, wr, wc, flags);
  k_b<<<N_ * C_ + N_ * 100, 256, 0, stream>>>(bxd, scd, lab, vld, rg, keepg,
                                              msig, wr, wc, flags, out);
}